// Round 9
// baseline (408.743 us; speedup 1.0000x reference)
//
#include <hip/hip_runtime.h>
#include <hip/hip_bf16.h>

#define NN 40000
#define EE 640000
#define ET 680000   // EE + NN self loops
#define MPAD 40064  // 313 * 128
#define LOG2E 1.4426950408889634f

typedef __attribute__((ext_vector_type(8))) short short8;
typedef __attribute__((ext_vector_type(4))) float f32x4;

__device__ __forceinline__ float bf2f(unsigned u) {
    return __uint_as_float(u << 16);
}
__device__ __forceinline__ unsigned short f2bf(float f) {
    unsigned u = __float_as_uint(f);
    return (unsigned short)((u + 0x7FFFu + ((u >> 16) & 1u)) >> 16);
}
__device__ __forceinline__ unsigned pack2(float lo, float hi) {
    return ((unsigned)f2bf(lo)) | (((unsigned)f2bf(hi)) << 16);
}
__device__ __forceinline__ void unpack2(unsigned u, float& lo, float& hi) {
    lo = __uint_as_float(u << 16);
    hi = __uint_as_float(u & 0xffff0000u);
}

// ---------------- converts ----------------
__global__ __launch_bounds__(256) void conv_x(const float* __restrict__ x,
                                              unsigned short* __restrict__ xb)
{
    int i = blockIdx.x * 256 + threadIdx.x;          // one per 4 elems
    if (i >= MPAD * 128 / 4) return;
    int row = (i * 4) >> 7;
    ushort4 o;
    if (row < NN) {
        float4 v = ((const float4*)x)[i];
        o.x = f2bf(v.x); o.y = f2bf(v.y); o.z = f2bf(v.z); o.w = f2bf(v.w);
    } else { o.x = o.y = o.z = o.w = 0; }
    ((ushort4*)xb)[i] = o;
}

// all weight transposes + attention-vector projections in one launch:
//  [0,32768)       : W0 [128][256]   -> W0t[256][128]
//  [32768,65536)   : W_skip          -> Wst[256][128]
//  [65536,131072)  : W1 [256][256]   -> W1t[256][256]
//  [131072,133120) : u[k][j] j<8: sum_c W0[k][h*32+c]*att_s0[h][c]; j>=8: att_d0  (x LOG2E)
//  [133120,133632) : v[k*2+w] = sum_c W1[k][c]*att1_{s,d}[c]  (x LOG2E)
__global__ __launch_bounds__(256) void conv_w_all(
    const float* __restrict__ W0, const float* __restrict__ Ws,
    const float* __restrict__ W1,
    const float* __restrict__ as0, const float* __restrict__ ad0,
    const float* __restrict__ as1, const float* __restrict__ ad1,
    unsigned short* __restrict__ W0t, unsigned short* __restrict__ Wst,
    unsigned short* __restrict__ W1t, float* __restrict__ u, float* __restrict__ v)
{
    int i = blockIdx.x * 256 + threadIdx.x;
    if (i < 32768) {
        int c = i >> 7, k = i & 127;
        W0t[i] = f2bf(W0[(size_t)k * 256 + c]);
    } else if (i < 65536) {
        int j = i - 32768;
        int c = j >> 7, k = j & 127;
        Wst[j] = f2bf(Ws[(size_t)k * 256 + c]);
    } else if (i < 131072) {
        int j = i - 65536;
        int c = j >> 8, k = j & 255;
        W1t[j] = f2bf(W1[(size_t)k * 256 + c]);
    } else if (i < 133120) {
        int j = i - 131072;          // [0,2048)
        int k = j >> 4, jj = j & 15;
        int h = jj & 7;
        const float* att = (jj < 8) ? as0 : ad0;
        float sum = 0.f;
        #pragma unroll
        for (int c = 0; c < 32; c++)
            sum += W0[(size_t)k * 256 + h * 32 + c] * att[h * 32 + c];
        u[j] = sum * LOG2E;
    } else if (i < 133632) {
        int j = i - 133120;          // [0,512)
        int k = j >> 1, which = j & 1;
        const float* att = which ? ad1 : as1;
        float sum = 0.f;
        for (int c = 0; c < 256; c++)
            sum += W1[(size_t)k * 256 + c] * att[c];
        v[j] = sum * LOG2E;
    }
}

// ---------------- MFMA GEMM (128x128 block): C = A[MPAD][K] @ Bt^T, bf16 out --------
__global__ __launch_bounds__(256) void gemm_bf16(
    const unsigned short* __restrict__ A, const unsigned short* __restrict__ Btc,
    unsigned short* __restrict__ C0, unsigned short* __restrict__ C1, int K)
{
    __shared__ unsigned short As[128 * 64];
    int tid = threadIdx.x;
    int rb = blockIdx.x * 128, cb = blockIdx.y * 128;
    int lane = tid & 63, wid = tid >> 6;
    int wm = (wid >> 1) * 64, wn = (wid & 1) * 64;
    int lr = lane & 15, lk = lane >> 4;
    f32x4 acc[4][4] = {};
    for (int kb = 0; kb < K; kb += 64) {
        #pragma unroll
        for (int i = 0; i < 4; i++) {
            int flat = tid + i * 256;
            int r = flat >> 3, c8 = flat & 7;
            int4 v = *(const int4*)(A + (size_t)(rb + r) * K + kb + c8 * 8);
            *(int4*)(&As[r * 64 + ((c8 ^ (r & 7)) * 8)]) = v;
        }
        __syncthreads();
        #pragma unroll
        for (int kk = 0; kk < 2; kk++) {
            int kbase = kb + kk * 32 + lk * 8;
            short8 bfr[4], afr[4];
            #pragma unroll
            for (int n = 0; n < 4; n++)
                bfr[n] = *(const short8*)(Btc + (size_t)(cb + wn + n * 16 + lr) * K + kbase);
            #pragma unroll
            for (int m = 0; m < 4; m++) {
                int row = wm + m * 16 + lr;
                int kchunk = kk * 4 + lk;
                afr[m] = *(const short8*)(&As[row * 64 + ((kchunk ^ (row & 7)) * 8)]);
            }
            #pragma unroll
            for (int m = 0; m < 4; m++)
                #pragma unroll
                for (int n = 0; n < 4; n++)
                    acc[m][n] = __builtin_amdgcn_mfma_f32_16x16x32_bf16(afr[m], bfr[n], acc[m][n], 0, 0, 0);
        }
        __syncthreads();
    }
    unsigned short* C = (cb < 256) ? C0 : C1;
    int cbase = cb & 255;
    #pragma unroll
    for (int m = 0; m < 4; m++)
        #pragma unroll
        for (int n = 0; n < 4; n++) {
            int col = cbase + wn + n * 16 + lr;
            #pragma unroll
            for (int j = 0; j < 4; j++) {
                int row = rb + wm + m * 16 + lk * 4 + j;
                C[(size_t)row * 256 + col] = f2bf(acc[m][n][j]);
            }
        }
}

// ---------------- block-diagonal GEMM: out0[:, h*32..] = agg[:, h*128..] @ W0t_h ----
__global__ __launch_bounds__(256) void gemm_agg0(
    const unsigned short* __restrict__ agg, const unsigned short* __restrict__ W0t,
    unsigned short* __restrict__ C)
{
    __shared__ unsigned short As[128 * 128];   // 32 KB
    int tid = threadIdx.x;
    int rb = blockIdx.x * 128;
    int hb = blockIdx.y;                       // head
    int lane = tid & 63, wid = tid >> 6;
    int lr = lane & 15, lk = lane >> 4;
    #pragma unroll
    for (int i = 0; i < 8; i++) {
        int flat = tid + i * 256;              // [0,2048)
        int r = flat >> 4, c8 = flat & 15;
        int4 v = *(const int4*)(agg + (size_t)(rb + r) * 1024 + hb * 128 + c8 * 8);
        *(int4*)(&As[r * 128 + ((c8 ^ (r & 7)) * 8)]) = v;
    }
    __syncthreads();
    f32x4 acc[2][2] = {};
    int wm = wid * 32;
    #pragma unroll
    for (int kk = 0; kk < 4; kk++) {
        int kbase = kk * 32 + lk * 8;
        short8 bfr[2], afr[2];
        #pragma unroll
        for (int n = 0; n < 2; n++)
            bfr[n] = *(const short8*)(W0t + (size_t)(hb * 32 + n * 16 + lr) * 128 + kbase);
        #pragma unroll
        for (int m = 0; m < 2; m++) {
            int row = wm + m * 16 + lr;
            int ck = kk * 4 + lk;
            afr[m] = *(const short8*)(&As[row * 128 + ((ck ^ (row & 7)) * 8)]);
        }
        #pragma unroll
        for (int m = 0; m < 2; m++)
            #pragma unroll
            for (int n = 0; n < 2; n++)
                acc[m][n] = __builtin_amdgcn_mfma_f32_16x16x32_bf16(afr[m], bfr[n], acc[m][n], 0, 0, 0);
    }
    #pragma unroll
    for (int m = 0; m < 2; m++)
        #pragma unroll
        for (int n = 0; n < 2; n++) {
            int col = hb * 32 + n * 16 + lr;
            #pragma unroll
            for (int j = 0; j < 4; j++) {
                int row = rb + wm + m * 16 + lk * 4 + j;
                C[(size_t)row * 256 + col] = f2bf(acc[m][n][j]);
            }
        }
}

// ---------------- final GEMM: out[NN][256] f32 = agg1 @ W1t^T + b1 ----------------
__global__ __launch_bounds__(256) void gemm_final(
    const unsigned short* __restrict__ A, const unsigned short* __restrict__ Btc,
    const float* __restrict__ b1, float* __restrict__ out)
{
    __shared__ unsigned short As[128 * 64];
    const int K = 256;
    int tid = threadIdx.x;
    int rb = blockIdx.x * 128, cb = blockIdx.y * 128;
    int lane = tid & 63, wid = tid >> 6;
    int wm = (wid >> 1) * 64, wn = (wid & 1) * 64;
    int lr = lane & 15, lk = lane >> 4;
    f32x4 acc[4][4] = {};
    for (int kb = 0; kb < K; kb += 64) {
        #pragma unroll
        for (int i = 0; i < 4; i++) {
            int flat = tid + i * 256;
            int r = flat >> 3, c8 = flat & 7;
            int4 v = *(const int4*)(A + (size_t)(rb + r) * K + kb + c8 * 8);
            *(int4*)(&As[r * 64 + ((c8 ^ (r & 7)) * 8)]) = v;
        }
        __syncthreads();
        #pragma unroll
        for (int kk = 0; kk < 2; kk++) {
            int kbase = kb + kk * 32 + lk * 8;
            short8 bfr[4], afr[4];
            #pragma unroll
            for (int n = 0; n < 4; n++)
                bfr[n] = *(const short8*)(Btc + (size_t)(cb + wn + n * 16 + lr) * K + kbase);
            #pragma unroll
            for (int m = 0; m < 4; m++) {
                int row = wm + m * 16 + lr;
                int kchunk = kk * 4 + lk;
                afr[m] = *(const short8*)(&As[row * 64 + ((kchunk ^ (row & 7)) * 8)]);
            }
            #pragma unroll
            for (int m = 0; m < 4; m++)
                #pragma unroll
                for (int n = 0; n < 4; n++)
                    acc[m][n] = __builtin_amdgcn_mfma_f32_16x16x32_bf16(afr[m], bfr[n], acc[m][n], 0, 0, 0);
        }
        __syncthreads();
    }
    #pragma unroll
    for (int n = 0; n < 4; n++) {
        int col = cb + wn + n * 16 + lr;
        float bc = b1[col];
        #pragma unroll
        for (int m = 0; m < 4; m++)
            #pragma unroll
            for (int j = 0; j < 4; j++) {
                int row = rb + wm + m * 16 + lk * 4 + j;
                if (row < NN)
                    out[(size_t)row * 256 + col] = acc[m][n][j] + bc;
            }
    }
}

// ---------------- CSR build (by dst) ----------------
__global__ __launch_bounds__(256) void csr_count(const int* __restrict__ ei, int* __restrict__ deg)
{
    int e = blockIdx.x * blockDim.x + threadIdx.x;
    if (e >= ET) return;
    int d = (e < EE) ? ei[EE + e] : (e - EE);
    atomicAdd(&deg[d], 1);
}

__global__ __launch_bounds__(1024) void exscan(
    const int* __restrict__ deg, int* __restrict__ rowptr, int* __restrict__ cursor)
{
    __shared__ int wsum[16];
    __shared__ int carry_s;
    int tid = threadIdx.x, lane = tid & 63, wid = tid >> 6;
    if (tid == 0) carry_s = 0;
    __syncthreads();
    for (int base = 0; base < NN; base += 1024) {
        int i = base + tid;
        int v = (i < NN) ? deg[i] : 0;
        int sc = v;
        #pragma unroll
        for (int off = 1; off < 64; off <<= 1) {
            int t = __shfl_up(sc, off);
            if (lane >= off) sc += t;
        }
        if (lane == 63) wsum[wid] = sc;
        __syncthreads();
        if (wid == 0 && lane < 16) {
            int t = wsum[lane];
            #pragma unroll
            for (int off = 1; off < 16; off <<= 1) {
                int u = __shfl_up(t, off);
                if (lane >= off) t += u;
            }
            wsum[lane] = t;
        }
        __syncthreads();
        int carry = carry_s;
        int wpre = wid ? wsum[wid - 1] : 0;
        int excl = carry + wpre + sc - v;
        if (i < NN) { rowptr[i] = excl; cursor[i] = excl; }
        __syncthreads();
        if (tid == 0) carry_s = carry + wsum[15];
    }
    if (tid == 0) rowptr[NN] = carry_s;
}

__global__ __launch_bounds__(256) void csr_fill(
    const int* __restrict__ ei, int* __restrict__ cursor, int* __restrict__ adj)
{
    int e = blockIdx.x * blockDim.x + threadIdx.x;
    if (e >= ET) return;
    int s, d;
    if (e < EE) { s = ei[e]; d = ei[EE + e]; } else { s = d = e - EE; }
    int pos = atomicAdd(&cursor[d], 1);
    adj[pos] = s;
}

// ---------------- layer-0 logits directly from x: a = x_bf @ u (wave per node) ------
__global__ __launch_bounds__(256) void attn0(
    const unsigned short* __restrict__ xb, const float* __restrict__ u,
    float* __restrict__ a_s, float* __restrict__ a_d)
{
    int w = (blockIdx.x * 256 + threadIdx.x) >> 6;
    int lane = threadIdx.x & 63;
    if (w >= NN) return;
    unsigned r = *(const unsigned*)(xb + (size_t)w * 128 + lane * 2);
    float x0, x1;
    unpack2(r, x0, x1);
    const float* u0 = u + (lane * 2) * 16;
    const float* u1 = u0 + 16;
    float ps[8], pd[8];
    #pragma unroll
    for (int h = 0; h < 8; h++) {
        ps[h] = x0 * u0[h] + x1 * u1[h];
        pd[h] = x0 * u0[8 + h] + x1 * u1[8 + h];
    }
    #pragma unroll
    for (int off = 1; off < 64; off <<= 1) {
        #pragma unroll
        for (int h = 0; h < 8; h++) {
            ps[h] += __shfl_xor(ps[h], off);
            pd[h] += __shfl_xor(pd[h], off);
        }
    }
    if (lane == 0) {
        #pragma unroll
        for (int h = 0; h < 8; h++) {
            a_s[w * 8 + h] = ps[h];
            a_d[w * 8 + h] = pd[h];
        }
    }
}

// ---------------- gather0p: aggregate raw x rows per head ----------------
// half-wave edges; lane covers 4 cols (8B) of the 128-col x row; acc[8 heads][4].
__global__ __launch_bounds__(256) void gather0p(
    const int* __restrict__ adj, const int* __restrict__ rowptr,
    const unsigned short* __restrict__ xb, const float* __restrict__ a_s,
    const float* __restrict__ a_d, unsigned short* __restrict__ agg)
{
    int w = (blockIdx.x * 256 + threadIdx.x) >> 6;
    int lane = threadIdx.x & 63;
    if (w >= NN) return;
    int hl = lane & 31, hw = lane >> 5;
    float4 adl0 = *(const float4*)(a_d + w * 8);
    float4 adl1 = *(const float4*)(a_d + w * 8 + 4);
    float ad[8] = {adl0.x, adl0.y, adl0.z, adl0.w, adl1.x, adl1.y, adl1.z, adl1.w};
    int p = rowptr[w], end = rowptr[w + 1];
    unsigned loff = (unsigned)hl * 8u;
    float acc[8][4] = {};
    float den[8] = {};
    for (; p + 2 <= end; p += 2) {
        int s = adj[p + hw];
        float4 as0 = *(const float4*)(a_s + s * 8);
        float4 as1 = *(const float4*)(a_s + s * 8 + 4);
        float as[8] = {as0.x, as0.y, as0.z, as0.w, as1.x, as1.y, as1.z, as1.w};
        uint2 r = *(const uint2*)((const char*)xb + ((unsigned)s * 256u + loff));
        float c0, c1, c2, c3;
        unpack2(r.x, c0, c1); unpack2(r.y, c2, c3);
        #pragma unroll
        for (int h = 0; h < 8; h++) {
            float e = as[h] + ad[h];
            float wt = __builtin_amdgcn_exp2f(fmaxf(e, 0.2f * e));
            den[h] += wt;
            acc[h][0] += wt * c0; acc[h][1] += wt * c1;
            acc[h][2] += wt * c2; acc[h][3] += wt * c3;
        }
    }
    if (p < end) {   // odd tail: half A only
        int s = adj[p];
        float4 as0 = *(const float4*)(a_s + s * 8);
        float4 as1 = *(const float4*)(a_s + s * 8 + 4);
        float as[8] = {as0.x, as0.y, as0.z, as0.w, as1.x, as1.y, as1.z, as1.w};
        uint2 r = *(const uint2*)((const char*)xb + ((unsigned)s * 256u + loff));
        float c0, c1, c2, c3;
        unpack2(r.x, c0, c1); unpack2(r.y, c2, c3);
        float m = hw ? 0.f : 1.f;
        #pragma unroll
        for (int h = 0; h < 8; h++) {
            float e = as[h] + ad[h];
            float wt = m * __builtin_amdgcn_exp2f(fmaxf(e, 0.2f * e));
            den[h] += wt;
            acc[h][0] += wt * c0; acc[h][1] += wt * c1;
            acc[h][2] += wt * c2; acc[h][3] += wt * c3;
        }
    }
    #pragma unroll
    for (int h = 0; h < 8; h++) {
        den[h] += __shfl_xor(den[h], 32);
        acc[h][0] += __shfl_xor(acc[h][0], 32);
        acc[h][1] += __shfl_xor(acc[h][1], 32);
        acc[h][2] += __shfl_xor(acc[h][2], 32);
        acc[h][3] += __shfl_xor(acc[h][3], 32);
    }
    if (hw == 0) {
        #pragma unroll
        for (int h = 0; h < 8; h++) {
            float inv = 1.f / (den[h] + 1e-16f);
            uint2 o;
            o.x = pack2(acc[h][0] * inv, acc[h][1] * inv);
            o.y = pack2(acc[h][2] * inv, acc[h][3] * inv);
            *(uint2*)((char*)agg + ((size_t)w * 2048u + h * 256u + loff)) = o;
        }
    }
}

// ---------------- BN column stats (bf16 input) ----------------
__global__ __launch_bounds__(256) void bn_stats(
    const unsigned short* __restrict__ H, float* __restrict__ bnsum, float* __restrict__ bnsq)
{
    int c = threadIdx.x;
    int r0 = blockIdx.x * 64;
    float s = 0.f, sq = 0.f;
    for (int r = r0; r < r0 + 64; r++) {
        float v = bf2f(H[(size_t)r * 256 + c]);
        s += v; sq += v * v;
    }
    atomicAdd(&bnsum[c], s);
    atomicAdd(&bnsq[c], sq);
}

// ---------------- h = elu(bn(out0)) + skip ; fused layer-1 logits a1 = h @ v --------
__global__ __launch_bounds__(256) void bn_elu_attn(
    const unsigned short* __restrict__ out0, unsigned short* __restrict__ hb,
    const float* __restrict__ bnsum, const float* __restrict__ bnsq,
    const float* __restrict__ gamma, const float* __restrict__ beta,
    const float* __restrict__ bskip, const float* __restrict__ v,
    float* __restrict__ a_s, float* __restrict__ a_d)
{
    int i = blockIdx.x * 256 + threadIdx.x;   // one per 8 elems; 32 threads per row
    if (i >= MPAD * 32) return;
    int col0 = (i * 8) & 255;
    int row = i >> 5;
    uint4 hv = ((const uint4*)out0)[i];
    uint4 sv = ((const uint4*)hb)[i];
    float bn[8], sk[8];
    unpack2(hv.x, bn[0], bn[1]); unpack2(hv.y, bn[2], bn[3]);
    unpack2(hv.z, bn[4], bn[5]); unpack2(hv.w, bn[6], bn[7]);
    unpack2(sv.x, sk[0], sk[1]); unpack2(sv.y, sk[2], sk[3]);
    unpack2(sv.z, sk[4], sk[5]); unpack2(sv.w, sk[6], sk[7]);
    const float invN = 1.0f / (float)NN;
    float r[8];
    float ps = 0.f, pd = 0.f;
    #pragma unroll
    for (int q = 0; q < 8; q++) {
        int c = col0 + q;
        float mu = bnsum[c] * invN;
        float var = bnsq[c] * invN - mu * mu;
        float scl = rsqrtf(var + 1e-5f) * gamma[c];
        float b = (bn[q] - mu) * scl + beta[c];
        float el = b > 0.f ? b : (__expf(b) - 1.f);
        r[q] = el + sk[q] + bskip[c];
        float2 vv = *(const float2*)(v + c * 2);
        ps += r[q] * vv.x;
        pd += r[q] * vv.y;
    }
    uint4 o;
    o.x = pack2(r[0], r[1]); o.y = pack2(r[2], r[3]);
    o.z = pack2(r[4], r[5]); o.w = pack2(r[6], r[7]);
    ((uint4*)hb)[i] = o;
    #pragma unroll
    for (int off = 1; off < 32; off <<= 1) {
        ps += __shfl_xor(ps, off);
        pd += __shfl_xor(pd, off);
    }
    if ((threadIdx.x & 31) == 0 && row < NN) {
        a_s[row] = ps;
        a_d[row] = pd;
    }
}

// ---------------- gather1p: aggregate h rows (1 head), bf16 agg1 out ----------------
__global__ __launch_bounds__(256) void gather1p(
    const int* __restrict__ adj, const int* __restrict__ rowptr,
    const unsigned short* __restrict__ hbuf, const float* __restrict__ a_s,
    const float* __restrict__ a_d, unsigned short* __restrict__ agg1)
{
    int w = (blockIdx.x * 256 + threadIdx.x) >> 6;
    int lane = threadIdx.x & 63;
    if (w >= NN) return;
    int hl = lane & 31;
    int hw = lane >> 5;
    float ad = a_d[w];
    int p = rowptr[w], end = rowptr[w + 1];
    unsigned loff = (unsigned)hl * 16u;
    float a0=0,a1=0,a2=0,a3=0,a4=0,a5=0,a6=0,a7=0;
    float b0=0,b1s=0,b2=0,b3=0,b4=0,b5=0,b6=0,b7=0;
    float den0 = 0.f, den1 = 0.f;
    float lo, hi;
    for (; p + 4 <= end; p += 4) {
        int sA = adj[p + hw];
        int sB = adj[p + 2 + hw];
        float eA = a_s[sA] + ad;
        float eB = a_s[sB] + ad;
        float wA = __builtin_amdgcn_exp2f(fmaxf(eA, 0.2f * eA));
        float wB = __builtin_amdgcn_exp2f(fmaxf(eB, 0.2f * eB));
        uint4 rA = *(const uint4*)((const char*)hbuf + ((unsigned)sA * 512u + loff));
        uint4 rB = *(const uint4*)((const char*)hbuf + ((unsigned)sB * 512u + loff));
        den0 += wA; den1 += wB;
        unpack2(rA.x, lo, hi); a0 += wA * lo; a1 += wA * hi;
        unpack2(rA.y, lo, hi); a2 += wA * lo; a3 += wA * hi;
        unpack2(rA.z, lo, hi); a4 += wA * lo; a5 += wA * hi;
        unpack2(rA.w, lo, hi); a6 += wA * lo; a7 += wA * hi;
        unpack2(rB.x, lo, hi); b0 += wB * lo; b1s += wB * hi;
        unpack2(rB.y, lo, hi); b2 += wB * lo; b3 += wB * hi;
        unpack2(rB.z, lo, hi); b4 += wB * lo; b5 += wB * hi;
        unpack2(rB.w, lo, hi); b6 += wB * lo; b7 += wB * hi;
    }
    for (; p + 2 <= end; p += 2) {
        int sA = adj[p + hw];
        float eA = a_s[sA] + ad;
        float wA = __builtin_amdgcn_exp2f(fmaxf(eA, 0.2f * eA));
        uint4 rA = *(const uint4*)((const char*)hbuf + ((unsigned)sA * 512u + loff));
        den0 += wA;
        unpack2(rA.x, lo, hi); a0 += wA * lo; a1 += wA * hi;
        unpack2(rA.y, lo, hi); a2 += wA * lo; a3 += wA * hi;
        unpack2(rA.z, lo, hi); a4 += wA * lo; a5 += wA * hi;
        unpack2(rA.w, lo, hi); a6 += wA * lo; a7 += wA * hi;
    }
    if (p < end) {
        int sA = adj[p];
        float eA = a_s[sA] + ad;
        float wA = hw ? 0.f : __builtin_amdgcn_exp2f(fmaxf(eA, 0.2f * eA));
        uint4 rA = *(const uint4*)((const char*)hbuf + ((unsigned)sA * 512u + loff));
        den0 += wA;
        unpack2(rA.x, lo, hi); a0 += wA * lo; a1 += wA * hi;
        unpack2(rA.y, lo, hi); a2 += wA * lo; a3 += wA * hi;
        unpack2(rA.z, lo, hi); a4 += wA * lo; a5 += wA * hi;
        unpack2(rA.w, lo, hi); a6 += wA * lo; a7 += wA * hi;
    }
    a0 += b0; a1 += b1s; a2 += b2; a3 += b3;
    a4 += b4; a5 += b5; a6 += b6; a7 += b7;
    float den = den0 + den1;
    den += __shfl_xor(den, 32);
    a0 += __shfl_xor(a0, 32); a1 += __shfl_xor(a1, 32);
    a2 += __shfl_xor(a2, 32); a3 += __shfl_xor(a3, 32);
    a4 += __shfl_xor(a4, 32); a5 += __shfl_xor(a5, 32);
    a6 += __shfl_xor(a6, 32); a7 += __shfl_xor(a7, 32);
    if (hw == 0) {
        float inv = 1.f / (den + 1e-16f);
        uint4 o;
        o.x = pack2(a0 * inv, a1 * inv);
        o.y = pack2(a2 * inv, a3 * inv);
        o.z = pack2(a4 * inv, a5 * inv);
        o.w = pack2(a6 * inv, a7 * inv);
        *(uint4*)((char*)agg1 + ((size_t)w * 512u + loff)) = o;
    }
}

extern "C" void kernel_launch(void* const* d_in, const int* in_sizes, int n_in,
                              void* d_out, int out_size, void* d_ws, size_t ws_size,
                              hipStream_t stream)
{
    const float* x      = (const float*)d_in[0];
    const int*   ei     = (const int*)d_in[1];
    const float* W0     = (const float*)d_in[2];
    const float* att_s0 = (const float*)d_in[3];
    const float* att_d0 = (const float*)d_in[4];
    // b0 (d_in[5]) cancels under BatchNorm -> unused
    const float* gamma0 = (const float*)d_in[6];
    const float* beta0  = (const float*)d_in[7];
    const float* W_skip = (const float*)d_in[8];
    const float* b_skip = (const float*)d_in[9];
    const float* W1     = (const float*)d_in[10];
    const float* att_s1 = (const float*)d_in[11];
    const float* att_d1 = (const float*)d_in[12];
    const float* b1     = (const float*)d_in[13];
    float* out = (float*)d_out;

    // workspace layout
    char* p = (char*)d_ws;
    unsigned short* x_bf  = (unsigned short*)p; p += (size_t)MPAD * 128 * 2;   // 10.25MB
    unsigned short* h_bf  = (unsigned short*)p; p += (size_t)MPAD * 256 * 2;   // 20.5MB
    unsigned short* out0b = (unsigned short*)p; p += (size_t)MPAD * 256 * 2;   // 20.5MB
    unsigned short* agg   = (unsigned short*)p; p += (size_t)MPAD * 1024 * 2;  // 82MB
    unsigned short* agg1  = agg;               // overlay: agg dead after gemm_agg0
    unsigned short* W0t = (unsigned short*)p; p += (size_t)256 * 128 * 2;
    unsigned short* Wst = (unsigned short*)p; p += (size_t)256 * 128 * 2;
    unsigned short* W1t = (unsigned short*)p; p += (size_t)256 * 256 * 2;
    float* u     = (float*)p; p += 2048 * 4;
    float* v     = (float*)p; p += 512 * 4;
    float* a_s   = (float*)p; p += (size_t)NN * 8 * 4;
    float* a_d   = (float*)p; p += (size_t)NN * 8 * 4;
    float* bnsum = (float*)p; p += 256 * 4;
    float* bnsq  = (float*)p; p += 256 * 4;
    int* deg    = (int*)p; p += (size_t)NN * 4;
    int* rowptr = (int*)p; p += (size_t)(NN + 1) * 4;
    int* cursor = (int*)p; p += (size_t)NN * 4;
    int* adj    = (int*)p; p += (size_t)ET * 4;

    hipMemsetAsync(deg, 0, (size_t)NN * 4, stream);
    hipMemsetAsync(bnsum, 0, 512 * 4, stream);

    // converts + projections
    conv_x<<<(MPAD * 128 / 4 + 255) / 256, 256, 0, stream>>>(x, x_bf);
    conv_w_all<<<(133632 + 255) / 256, 256, 0, stream>>>(
        W0, W_skip, W1, att_s0, att_d0, att_s1, att_d1, W0t, Wst, W1t, u, v);

    // CSR build
    csr_count<<<(ET + 255) / 256, 256, 0, stream>>>(ei, deg);
    exscan<<<1, 1024, 0, stream>>>(deg, rowptr, cursor);
    csr_fill<<<(ET + 255) / 256, 256, 0, stream>>>(ei, cursor, adj);

    // ---- layer 0 (aggregate-then-project) ----
    attn0<<<(NN * 64 + 255) / 256, 256, 0, stream>>>(x_bf, u, a_s, a_d);
    gather0p<<<(NN * 64 + 255) / 256, 256, 0, stream>>>(adj, rowptr, x_bf, a_s, a_d, agg);
    dim3 ga(MPAD / 128, 8);
    gemm_agg0<<<ga, 256, 0, stream>>>(agg, W0t, out0b);

    // ---- skip projection ----
    dim3 gs(MPAD / 128, 2);
    gemm_bf16<<<gs, 256, 0, stream>>>(x_bf, Wst, h_bf, h_bf, 128);

    // ---- BN + ELU + skip, fused layer-1 logits ----
    bn_stats<<<NN / 64, 256, 0, stream>>>(out0b, bnsum, bnsq);
    bn_elu_attn<<<(MPAD * 32 + 255) / 256, 256, 0, stream>>>(
        out0b, h_bf, bnsum, bnsq, gamma0, beta0, b_skip, v, a_s, a_d);

    // ---- layer 1 (aggregate-then-project) ----
    gather1p<<<(NN * 64 + 255) / 256, 256, 0, stream>>>(adj, rowptr, h_bf, a_s, a_d, agg1);
    dim3 gf(MPAD / 128, 2);
    gemm_final<<<gf, 256, 0, stream>>>(agg1, W1t, b1, out);
}

// Round 10
// 355.617 us; speedup vs baseline: 1.1494x; 1.1494x over previous
//
#include <hip/hip_runtime.h>
#include <hip/hip_bf16.h>

#define NN 40000
#define EE 640000
#define ET 680000   // EE + NN self loops
#define MPAD 40064  // 313 * 128
#define LOG2E 1.4426950408889634f

typedef __attribute__((ext_vector_type(8))) short short8;
typedef __attribute__((ext_vector_type(4))) float f32x4;

__device__ __forceinline__ float bf2f(unsigned u) {
    return __uint_as_float(u << 16);
}
__device__ __forceinline__ unsigned short f2bf(float f) {
    unsigned u = __float_as_uint(f);
    return (unsigned short)((u + 0x7FFFu + ((u >> 16) & 1u)) >> 16);
}
__device__ __forceinline__ unsigned pack2(float lo, float hi) {
    return ((unsigned)f2bf(lo)) | (((unsigned)f2bf(hi)) << 16);
}
__device__ __forceinline__ void unpack2(unsigned u, float& lo, float& hi) {
    lo = __uint_as_float(u << 16);
    hi = __uint_as_float(u & 0xffff0000u);
}

// ---------------- converts ----------------
__global__ __launch_bounds__(256) void conv_x(const float* __restrict__ x,
                                              unsigned short* __restrict__ xb)
{
    int i = blockIdx.x * 256 + threadIdx.x;          // one per 4 elems
    if (i >= MPAD * 128 / 4) return;
    int row = (i * 4) >> 7;
    ushort4 o;
    if (row < NN) {
        float4 v = ((const float4*)x)[i];
        o.x = f2bf(v.x); o.y = f2bf(v.y); o.z = f2bf(v.z); o.w = f2bf(v.w);
    } else { o.x = o.y = o.z = o.w = 0; }
    ((ushort4*)xb)[i] = o;
}

// weight transposes + attention-vector projections in one launch:
//  [0,32768)       : W0 [128][256]   -> Wtc[0..][256 cols x 128]
//  [32768,65536)   : W_skip          -> Wtc+32768
//  [65536,131072)  : W1 [256][256]   -> W1t[256][256]
//  [131072,133120) : u[k*16+j] j<8: sum_c W0[k][h*32+c]*att_s0[h][c]; j>=8: att_d0 (xLOG2E)
//  [133120,133632) : v[k*2+w] = sum_c W1[k][c]*att1_{s,d}[c]  (xLOG2E)
__global__ __launch_bounds__(256) void conv_w_all(
    const float* __restrict__ W0, const float* __restrict__ Ws,
    const float* __restrict__ W1,
    const float* __restrict__ as0, const float* __restrict__ ad0,
    const float* __restrict__ as1, const float* __restrict__ ad1,
    unsigned short* __restrict__ Wtc, unsigned short* __restrict__ W1t,
    float* __restrict__ u, float* __restrict__ v)
{
    int i = blockIdx.x * 256 + threadIdx.x;
    if (i < 32768) {
        int c = i >> 7, k = i & 127;
        Wtc[i] = f2bf(W0[(size_t)k * 256 + c]);
    } else if (i < 65536) {
        int j = i - 32768;
        int c = j >> 7, k = j & 127;
        Wtc[i] = f2bf(Ws[(size_t)k * 256 + c]);
    } else if (i < 131072) {
        int j = i - 65536;
        int c = j >> 8, k = j & 255;
        W1t[j] = f2bf(W1[(size_t)k * 256 + c]);
    } else if (i < 133120) {
        int j = i - 131072;          // [0,2048)
        int k = j >> 4, jj = j & 15;
        int h = jj & 7;
        const float* att = (jj < 8) ? as0 : ad0;
        float sum = 0.f;
        #pragma unroll
        for (int c = 0; c < 32; c++)
            sum += W0[(size_t)k * 256 + h * 32 + c] * att[h * 32 + c];
        u[j] = sum * LOG2E;
    } else if (i < 133632) {
        int j = i - 133120;          // [0,512)
        int k = j >> 1, which = j & 1;
        const float* att = which ? ad1 : as1;
        float sum = 0.f;
        for (int c = 0; c < 256; c++)
            sum += W1[(size_t)k * 256 + c] * att[c];
        v[j] = sum * LOG2E;
    }
}

// ---------------- MFMA GEMM: Cd[MPAD][256] = A[MPAD][K] @ Bt^T (dual output) ----------
__global__ __launch_bounds__(256) void gemm_bf16(
    const unsigned short* __restrict__ A, const unsigned short* __restrict__ Btc,
    unsigned short* __restrict__ C0, unsigned short* __restrict__ C1, int K)
{
    __shared__ unsigned short As[128 * 64];
    int tid = threadIdx.x;
    int rb = blockIdx.x * 128, cb = blockIdx.y * 128;
    int lane = tid & 63, wid = tid >> 6;
    int wm = (wid >> 1) * 64, wn = (wid & 1) * 64;
    int lr = lane & 15, lk = lane >> 4;
    f32x4 acc[4][4] = {};
    for (int kb = 0; kb < K; kb += 64) {
        #pragma unroll
        for (int i = 0; i < 4; i++) {
            int flat = tid + i * 256;
            int r = flat >> 3, c8 = flat & 7;
            int4 v = *(const int4*)(A + (size_t)(rb + r) * K + kb + c8 * 8);
            *(int4*)(&As[r * 64 + ((c8 ^ (r & 7)) * 8)]) = v;
        }
        __syncthreads();
        #pragma unroll
        for (int kk = 0; kk < 2; kk++) {
            int kbase = kb + kk * 32 + lk * 8;
            short8 bfr[4], afr[4];
            #pragma unroll
            for (int n = 0; n < 4; n++)
                bfr[n] = *(const short8*)(Btc + (size_t)(cb + wn + n * 16 + lr) * K + kbase);
            #pragma unroll
            for (int m = 0; m < 4; m++) {
                int row = wm + m * 16 + lr;
                int kchunk = kk * 4 + lk;
                afr[m] = *(const short8*)(&As[row * 64 + ((kchunk ^ (row & 7)) * 8)]);
            }
            #pragma unroll
            for (int m = 0; m < 4; m++)
                #pragma unroll
                for (int n = 0; n < 4; n++)
                    acc[m][n] = __builtin_amdgcn_mfma_f32_16x16x32_bf16(afr[m], bfr[n], acc[m][n], 0, 0, 0);
        }
        __syncthreads();
    }
    unsigned short* C = (cb < 256) ? C0 : C1;
    int cbase = cb & 255;
    #pragma unroll
    for (int m = 0; m < 4; m++)
        #pragma unroll
        for (int n = 0; n < 4; n++) {
            int col = cbase + wn + n * 16 + lr;
            #pragma unroll
            for (int j = 0; j < 4; j++) {
                int row = rb + wm + m * 16 + lk * 4 + j;
                C[(size_t)row * 256 + col] = f2bf(acc[m][n][j]);
            }
        }
}

// ---------------- final GEMM: out[NN][256] f32 = agg1 @ W1t^T + b1 ----------------
__global__ __launch_bounds__(256) void gemm_final(
    const unsigned short* __restrict__ A, const unsigned short* __restrict__ Btc,
    const float* __restrict__ b1, float* __restrict__ out)
{
    __shared__ unsigned short As[128 * 64];
    const int K = 256;
    int tid = threadIdx.x;
    int rb = blockIdx.x * 128, cb = blockIdx.y * 128;
    int lane = tid & 63, wid = tid >> 6;
    int wm = (wid >> 1) * 64, wn = (wid & 1) * 64;
    int lr = lane & 15, lk = lane >> 4;
    f32x4 acc[4][4] = {};
    for (int kb = 0; kb < K; kb += 64) {
        #pragma unroll
        for (int i = 0; i < 4; i++) {
            int flat = tid + i * 256;
            int r = flat >> 3, c8 = flat & 7;
            int4 v = *(const int4*)(A + (size_t)(rb + r) * K + kb + c8 * 8);
            *(int4*)(&As[r * 64 + ((c8 ^ (r & 7)) * 8)]) = v;
        }
        __syncthreads();
        #pragma unroll
        for (int kk = 0; kk < 2; kk++) {
            int kbase = kb + kk * 32 + lk * 8;
            short8 bfr[4], afr[4];
            #pragma unroll
            for (int n = 0; n < 4; n++)
                bfr[n] = *(const short8*)(Btc + (size_t)(cb + wn + n * 16 + lr) * K + kbase);
            #pragma unroll
            for (int m = 0; m < 4; m++) {
                int row = wm + m * 16 + lr;
                int kchunk = kk * 4 + lk;
                afr[m] = *(const short8*)(&As[row * 64 + ((kchunk ^ (row & 7)) * 8)]);
            }
            #pragma unroll
            for (int m = 0; m < 4; m++)
                #pragma unroll
                for (int n = 0; n < 4; n++)
                    acc[m][n] = __builtin_amdgcn_mfma_f32_16x16x32_bf16(afr[m], bfr[n], acc[m][n], 0, 0, 0);
        }
        __syncthreads();
    }
    #pragma unroll
    for (int n = 0; n < 4; n++) {
        int col = cb + wn + n * 16 + lr;
        float bc = b1[col];
        #pragma unroll
        for (int m = 0; m < 4; m++)
            #pragma unroll
            for (int j = 0; j < 4; j++) {
                int row = rb + wm + m * 16 + lk * 4 + j;
                if (row < NN)
                    out[(size_t)row * 256 + col] = acc[m][n][j] + bc;
            }
    }
}

// ---------------- CSR build (by dst) ----------------
__global__ __launch_bounds__(256) void csr_count(const int* __restrict__ ei, int* __restrict__ deg)
{
    int e = blockIdx.x * blockDim.x + threadIdx.x;
    if (e >= ET) return;
    int d = (e < EE) ? ei[EE + e] : (e - EE);
    atomicAdd(&deg[d], 1);
}

__global__ __launch_bounds__(1024) void exscan(
    const int* __restrict__ deg, int* __restrict__ rowptr, int* __restrict__ cursor)
{
    __shared__ int wsum[16];
    __shared__ int carry_s;
    int tid = threadIdx.x, lane = tid & 63, wid = tid >> 6;
    if (tid == 0) carry_s = 0;
    __syncthreads();
    for (int base = 0; base < NN; base += 1024) {
        int i = base + tid;
        int v = (i < NN) ? deg[i] : 0;
        int sc = v;
        #pragma unroll
        for (int off = 1; off < 64; off <<= 1) {
            int t = __shfl_up(sc, off);
            if (lane >= off) sc += t;
        }
        if (lane == 63) wsum[wid] = sc;
        __syncthreads();
        if (wid == 0 && lane < 16) {
            int t = wsum[lane];
            #pragma unroll
            for (int off = 1; off < 16; off <<= 1) {
                int u = __shfl_up(t, off);
                if (lane >= off) t += u;
            }
            wsum[lane] = t;
        }
        __syncthreads();
        int carry = carry_s;
        int wpre = wid ? wsum[wid - 1] : 0;
        int excl = carry + wpre + sc - v;
        if (i < NN) { rowptr[i] = excl; cursor[i] = excl; }
        __syncthreads();
        if (tid == 0) carry_s = carry + wsum[15];
    }
    if (tid == 0) rowptr[NN] = carry_s;
}

__global__ __launch_bounds__(256) void csr_fill(
    const int* __restrict__ ei, int* __restrict__ cursor, int* __restrict__ adj)
{
    int e = blockIdx.x * blockDim.x + threadIdx.x;
    if (e >= ET) return;
    int s, d;
    if (e < EE) { s = ei[e]; d = ei[EE + e]; } else { s = d = e - EE; }
    int pos = atomicAdd(&cursor[d], 1);
    adj[pos] = s;
}

// ---------------- layer-0 logits directly from x: a = x_bf @ u (wave per node) ------
__global__ __launch_bounds__(256) void attn0(
    const unsigned short* __restrict__ xb, const float* __restrict__ u,
    float* __restrict__ a_s, float* __restrict__ a_d)
{
    int w = (blockIdx.x * 256 + threadIdx.x) >> 6;
    int lane = threadIdx.x & 63;
    if (w >= NN) return;
    unsigned r = *(const unsigned*)(xb + (size_t)w * 128 + lane * 2);
    float x0, x1;
    unpack2(r, x0, x1);
    const float* u0 = u + (lane * 2) * 16;
    const float* u1 = u0 + 16;
    float ps[8], pd[8];
    #pragma unroll
    for (int h = 0; h < 8; h++) {
        ps[h] = x0 * u0[h] + x1 * u1[h];
        pd[h] = x0 * u0[8 + h] + x1 * u1[8 + h];
    }
    #pragma unroll
    for (int off = 1; off < 64; off <<= 1) {
        #pragma unroll
        for (int h = 0; h < 8; h++) {
            ps[h] += __shfl_xor(ps[h], off);
            pd[h] += __shfl_xor(pd[h], off);
        }
    }
    if (lane == 0) {
        #pragma unroll
        for (int h = 0; h < 8; h++) {
            a_s[w * 8 + h] = ps[h];
            a_d[w * 8 + h] = pd[h];
        }
    }
}

// ---------------- gather0: half-wave edges on xp, 8 ch/lane (R8-proven) ------------
__global__ __launch_bounds__(256) void gather0(
    const int* __restrict__ adj, const int* __restrict__ rowptr,
    const unsigned short* __restrict__ xp, const float* __restrict__ a_s,
    const float* __restrict__ a_d, unsigned short* __restrict__ out0)
{
    int w = (blockIdx.x * 256 + threadIdx.x) >> 6;
    int lane = threadIdx.x & 63;
    if (w >= NN) return;
    int hl = lane & 31;               // half-lane
    int hw = lane >> 5;               // which half-wave
    int h = hl >> 2;                  // head = (8*hl)/32
    float ad = a_d[w * 8 + h];
    int p = rowptr[w], end = rowptr[w + 1];
    unsigned loff = (unsigned)hl * 16u;
    float a0=0,a1=0,a2=0,a3=0,a4=0,a5=0,a6=0,a7=0;
    float b0=0,b1=0,b2=0,b3=0,b4=0,b5=0,b6=0,b7=0;
    float den0 = 0.f, den1 = 0.f;
    float lo, hi;
    for (; p + 4 <= end; p += 4) {
        int sA = adj[p + hw];
        int sB = adj[p + 2 + hw];
        float eA = a_s[sA * 8 + h] + ad;
        float eB = a_s[sB * 8 + h] + ad;
        float wA = __builtin_amdgcn_exp2f(fmaxf(eA, 0.2f * eA));
        float wB = __builtin_amdgcn_exp2f(fmaxf(eB, 0.2f * eB));
        uint4 rA = *(const uint4*)((const char*)xp + ((unsigned)sA * 512u + loff));
        uint4 rB = *(const uint4*)((const char*)xp + ((unsigned)sB * 512u + loff));
        den0 += wA; den1 += wB;
        unpack2(rA.x, lo, hi); a0 += wA * lo; a1 += wA * hi;
        unpack2(rA.y, lo, hi); a2 += wA * lo; a3 += wA * hi;
        unpack2(rA.z, lo, hi); a4 += wA * lo; a5 += wA * hi;
        unpack2(rA.w, lo, hi); a6 += wA * lo; a7 += wA * hi;
        unpack2(rB.x, lo, hi); b0 += wB * lo; b1 += wB * hi;
        unpack2(rB.y, lo, hi); b2 += wB * lo; b3 += wB * hi;
        unpack2(rB.z, lo, hi); b4 += wB * lo; b5 += wB * hi;
        unpack2(rB.w, lo, hi); b6 += wB * lo; b7 += wB * hi;
    }
    for (; p + 2 <= end; p += 2) {
        int sA = adj[p + hw];
        float eA = a_s[sA * 8 + h] + ad;
        float wA = __builtin_amdgcn_exp2f(fmaxf(eA, 0.2f * eA));
        uint4 rA = *(const uint4*)((const char*)xp + ((unsigned)sA * 512u + loff));
        den0 += wA;
        unpack2(rA.x, lo, hi); a0 += wA * lo; a1 += wA * hi;
        unpack2(rA.y, lo, hi); a2 += wA * lo; a3 += wA * hi;
        unpack2(rA.z, lo, hi); a4 += wA * lo; a5 += wA * hi;
        unpack2(rA.w, lo, hi); a6 += wA * lo; a7 += wA * hi;
    }
    if (p < end) {                     // single tail edge: half A only
        int sA = adj[p];
        float eA = a_s[sA * 8 + h] + ad;
        float wA = hw ? 0.f : __builtin_amdgcn_exp2f(fmaxf(eA, 0.2f * eA));
        uint4 rA = *(const uint4*)((const char*)xp + ((unsigned)sA * 512u + loff));
        den0 += wA;
        unpack2(rA.x, lo, hi); a0 += wA * lo; a1 += wA * hi;
        unpack2(rA.y, lo, hi); a2 += wA * lo; a3 += wA * hi;
        unpack2(rA.z, lo, hi); a4 += wA * lo; a5 += wA * hi;
        unpack2(rA.w, lo, hi); a6 += wA * lo; a7 += wA * hi;
    }
    a0 += b0; a1 += b1; a2 += b2; a3 += b3;
    a4 += b4; a5 += b5; a6 += b6; a7 += b7;
    float den = den0 + den1;
    den += __shfl_xor(den, 32);
    a0 += __shfl_xor(a0, 32); a1 += __shfl_xor(a1, 32);
    a2 += __shfl_xor(a2, 32); a3 += __shfl_xor(a3, 32);
    a4 += __shfl_xor(a4, 32); a5 += __shfl_xor(a5, 32);
    a6 += __shfl_xor(a6, 32); a7 += __shfl_xor(a7, 32);
    if (hw == 0) {
        float inv = 1.f / (den + 1e-16f);
        uint4 o;
        o.x = pack2(a0 * inv, a1 * inv);
        o.y = pack2(a2 * inv, a3 * inv);
        o.z = pack2(a4 * inv, a5 * inv);
        o.w = pack2(a6 * inv, a7 * inv);
        *(uint4*)((char*)out0 + ((size_t)w * 512u + loff)) = o;
    }
}

// ---------------- BN column stats (bf16 input) ----------------
__global__ __launch_bounds__(256) void bn_stats(
    const unsigned short* __restrict__ H, float* __restrict__ bnsum, float* __restrict__ bnsq)
{
    int c = threadIdx.x;
    int r0 = blockIdx.x * 64;
    float s = 0.f, sq = 0.f;
    for (int r = r0; r < r0 + 64; r++) {
        float v = bf2f(H[(size_t)r * 256 + c]);
        s += v; sq += v * v;
    }
    atomicAdd(&bnsum[c], s);
    atomicAdd(&bnsq[c], sq);
}

// ---------------- h = elu(bn(out0)) + skip ; fused layer-1 logits a1 = h @ v --------
__global__ __launch_bounds__(256) void bn_elu_attn(
    const unsigned short* __restrict__ out0, unsigned short* __restrict__ hb,
    const float* __restrict__ bnsum, const float* __restrict__ bnsq,
    const float* __restrict__ gamma, const float* __restrict__ beta,
    const float* __restrict__ bskip, const float* __restrict__ v,
    float* __restrict__ a_s, float* __restrict__ a_d)
{
    int i = blockIdx.x * 256 + threadIdx.x;   // one per 8 elems; 32 threads per row
    if (i >= MPAD * 32) return;
    int col0 = (i * 8) & 255;
    int row = i >> 5;
    uint4 hv = ((const uint4*)out0)[i];
    uint4 sv = ((const uint4*)hb)[i];
    float bn[8], sk[8];
    unpack2(hv.x, bn[0], bn[1]); unpack2(hv.y, bn[2], bn[3]);
    unpack2(hv.z, bn[4], bn[5]); unpack2(hv.w, bn[6], bn[7]);
    unpack2(sv.x, sk[0], sk[1]); unpack2(sv.y, sk[2], sk[3]);
    unpack2(sv.z, sk[4], sk[5]); unpack2(sv.w, sk[6], sk[7]);
    const float invN = 1.0f / (float)NN;
    float r[8];
    float ps = 0.f, pd = 0.f;
    #pragma unroll
    for (int q = 0; q < 8; q++) {
        int c = col0 + q;
        float mu = bnsum[c] * invN;
        float var = bnsq[c] * invN - mu * mu;
        float scl = rsqrtf(var + 1e-5f) * gamma[c];
        float b = (bn[q] - mu) * scl + beta[c];
        float el = b > 0.f ? b : (__expf(b) - 1.f);
        r[q] = el + sk[q] + bskip[c];
        float2 vv = *(const float2*)(v + c * 2);
        ps += r[q] * vv.x;
        pd += r[q] * vv.y;
    }
    uint4 o;
    o.x = pack2(r[0], r[1]); o.y = pack2(r[2], r[3]);
    o.z = pack2(r[4], r[5]); o.w = pack2(r[6], r[7]);
    ((uint4*)hb)[i] = o;
    #pragma unroll
    for (int off = 1; off < 32; off <<= 1) {
        ps += __shfl_xor(ps, off);
        pd += __shfl_xor(pd, off);
    }
    if ((threadIdx.x & 31) == 0 && row < NN) {
        a_s[row] = ps;
        a_d[row] = pd;
    }
}

// ---------------- gather1p: aggregate h rows (1 head), bf16 agg1 out ----------------
__global__ __launch_bounds__(256) void gather1p(
    const int* __restrict__ adj, const int* __restrict__ rowptr,
    const unsigned short* __restrict__ hbuf, const float* __restrict__ a_s,
    const float* __restrict__ a_d, unsigned short* __restrict__ agg1)
{
    int w = (blockIdx.x * 256 + threadIdx.x) >> 6;
    int lane = threadIdx.x & 63;
    if (w >= NN) return;
    int hl = lane & 31;
    int hw = lane >> 5;
    float ad = a_d[w];
    int p = rowptr[w], end = rowptr[w + 1];
    unsigned loff = (unsigned)hl * 16u;
    float a0=0,a1=0,a2=0,a3=0,a4=0,a5=0,a6=0,a7=0;
    float b0=0,b1s=0,b2=0,b3=0,b4=0,b5=0,b6=0,b7=0;
    float den0 = 0.f, den1 = 0.f;
    float lo, hi;
    for (; p + 4 <= end; p += 4) {
        int sA = adj[p + hw];
        int sB = adj[p + 2 + hw];
        float eA = a_s[sA] + ad;
        float eB = a_s[sB] + ad;
        float wA = __builtin_amdgcn_exp2f(fmaxf(eA, 0.2f * eA));
        float wB = __builtin_amdgcn_exp2f(fmaxf(eB, 0.2f * eB));
        uint4 rA = *(const uint4*)((const char*)hbuf + ((unsigned)sA * 512u + loff));
        uint4 rB = *(const uint4*)((const char*)hbuf + ((unsigned)sB * 512u + loff));
        den0 += wA; den1 += wB;
        unpack2(rA.x, lo, hi); a0 += wA * lo; a1 += wA * hi;
        unpack2(rA.y, lo, hi); a2 += wA * lo; a3 += wA * hi;
        unpack2(rA.z, lo, hi); a4 += wA * lo; a5 += wA * hi;
        unpack2(rA.w, lo, hi); a6 += wA * lo; a7 += wA * hi;
        unpack2(rB.x, lo, hi); b0 += wB * lo; b1s += wB * hi;
        unpack2(rB.y, lo, hi); b2 += wB * lo; b3 += wB * hi;
        unpack2(rB.z, lo, hi); b4 += wB * lo; b5 += wB * hi;
        unpack2(rB.w, lo, hi); b6 += wB * lo; b7 += wB * hi;
    }
    for (; p + 2 <= end; p += 2) {
        int sA = adj[p + hw];
        float eA = a_s[sA] + ad;
        float wA = __builtin_amdgcn_exp2f(fmaxf(eA, 0.2f * eA));
        uint4 rA = *(const uint4*)((const char*)hbuf + ((unsigned)sA * 512u + loff));
        den0 += wA;
        unpack2(rA.x, lo, hi); a0 += wA * lo; a1 += wA * hi;
        unpack2(rA.y, lo, hi); a2 += wA * lo; a3 += wA * hi;
        unpack2(rA.z, lo, hi); a4 += wA * lo; a5 += wA * hi;
        unpack2(rA.w, lo, hi); a6 += wA * lo; a7 += wA * hi;
    }
    if (p < end) {
        int sA = adj[p];
        float eA = a_s[sA] + ad;
        float wA = hw ? 0.f : __builtin_amdgcn_exp2f(fmaxf(eA, 0.2f * eA));
        uint4 rA = *(const uint4*)((const char*)hbuf + ((unsigned)sA * 512u + loff));
        den0 += wA;
        unpack2(rA.x, lo, hi); a0 += wA * lo; a1 += wA * hi;
        unpack2(rA.y, lo, hi); a2 += wA * lo; a3 += wA * hi;
        unpack2(rA.z, lo, hi); a4 += wA * lo; a5 += wA * hi;
        unpack2(rA.w, lo, hi); a6 += wA * lo; a7 += wA * hi;
    }
    a0 += b0; a1 += b1s; a2 += b2; a3 += b3;
    a4 += b4; a5 += b5; a6 += b6; a7 += b7;
    float den = den0 + den1;
    den += __shfl_xor(den, 32);
    a0 += __shfl_xor(a0, 32); a1 += __shfl_xor(a1, 32);
    a2 += __shfl_xor(a2, 32); a3 += __shfl_xor(a3, 32);
    a4 += __shfl_xor(a4, 32); a5 += __shfl_xor(a5, 32);
    a6 += __shfl_xor(a6, 32); a7 += __shfl_xor(a7, 32);
    if (hw == 0) {
        float inv = 1.f / (den + 1e-16f);
        uint4 o;
        o.x = pack2(a0 * inv, a1 * inv);
        o.y = pack2(a2 * inv, a3 * inv);
        o.z = pack2(a4 * inv, a5 * inv);
        o.w = pack2(a6 * inv, a7 * inv);
        *(uint4*)((char*)agg1 + ((size_t)w * 512u + loff)) = o;
    }
}

extern "C" void kernel_launch(void* const* d_in, const int* in_sizes, int n_in,
                              void* d_out, int out_size, void* d_ws, size_t ws_size,
                              hipStream_t stream)
{
    const float* x      = (const float*)d_in[0];
    const int*   ei     = (const int*)d_in[1];
    const float* W0     = (const float*)d_in[2];
    const float* att_s0 = (const float*)d_in[3];
    const float* att_d0 = (const float*)d_in[4];
    // b0 (d_in[5]) cancels under BatchNorm -> unused
    const float* gamma0 = (const float*)d_in[6];
    const float* beta0  = (const float*)d_in[7];
    const float* W_skip = (const float*)d_in[8];
    const float* b_skip = (const float*)d_in[9];
    const float* W1     = (const float*)d_in[10];
    const float* att_s1 = (const float*)d_in[11];
    const float* att_d1 = (const float*)d_in[12];
    const float* b1     = (const float*)d_in[13];
    float* out = (float*)d_out;

    // workspace layout
    char* p = (char*)d_ws;
    unsigned short* x_bf  = (unsigned short*)p; p += (size_t)MPAD * 128 * 2;
    unsigned short* xp_bf = (unsigned short*)p; p += (size_t)MPAD * 256 * 2;  // xp0, later agg1
    unsigned short* h_bf  = (unsigned short*)p; p += (size_t)MPAD * 256 * 2;  // skip, then h
    unsigned short* out0b = (unsigned short*)p; p += (size_t)MPAD * 256 * 2;
    unsigned short* Wtc   = (unsigned short*)p; p += (size_t)512 * 128 * 2;   // [W0t | Wst]
    unsigned short* W1t   = (unsigned short*)p; p += (size_t)256 * 256 * 2;
    float* u     = (float*)p; p += 2048 * 4;
    float* v     = (float*)p; p += 512 * 4;
    float* a_s   = (float*)p; p += (size_t)NN * 8 * 4;
    float* a_d   = (float*)p; p += (size_t)NN * 8 * 4;
    float* bnsum = (float*)p; p += 256 * 4;
    float* bnsq  = (float*)p; p += 256 * 4;
    int* deg    = (int*)p; p += (size_t)NN * 4;
    int* rowptr = (int*)p; p += (size_t)(NN + 1) * 4;
    int* cursor = (int*)p; p += (size_t)NN * 4;
    int* adj    = (int*)p; p += (size_t)ET * 4;

    hipMemsetAsync(deg, 0, (size_t)NN * 4, stream);
    hipMemsetAsync(bnsum, 0, 512 * 4, stream);
    // deterministic pad rows for out0b (never written by gather0)
    hipMemsetAsync(out0b + (size_t)NN * 256, 0, (size_t)(MPAD - NN) * 256 * 2, stream);

    // converts + projections
    conv_x<<<(MPAD * 128 / 4 + 255) / 256, 256, 0, stream>>>(x, x_bf);
    conv_w_all<<<(133632 + 255) / 256, 256, 0, stream>>>(
        W0, W_skip, W1, att_s0, att_d0, att_s1, att_d1, Wtc, W1t, u, v);

    // CSR build
    csr_count<<<(ET + 255) / 256, 256, 0, stream>>>(ei, deg);
    exscan<<<1, 1024, 0, stream>>>(deg, rowptr, cursor);
    csr_fill<<<(ET + 255) / 256, 256, 0, stream>>>(ei, cursor, adj);

    // ---- layer 0: combined GEMM (xp | skip), logits from x ----
    dim3 gg0(MPAD / 128, 4);
    gemm_bf16<<<gg0, 256, 0, stream>>>(x_bf, Wtc, xp_bf, h_bf, 128);
    attn0<<<(NN * 64 + 255) / 256, 256, 0, stream>>>(x_bf, u, a_s, a_d);
    gather0<<<(NN * 64 + 255) / 256, 256, 0, stream>>>(adj, rowptr, xp_bf, a_s, a_d, out0b);

    // ---- BN + ELU + skip, fused layer-1 logits ----
    bn_stats<<<NN / 64, 256, 0, stream>>>(out0b, bnsum, bnsq);
    bn_elu_attn<<<(MPAD * 32 + 255) / 256, 256, 0, stream>>>(
        out0b, h_bf, bnsum, bnsq, gamma0, beta0, b_skip, v, a_s, a_d);

    // ---- layer 1 (aggregate-then-project); agg1 overlays dead xp_bf ----
    gather1p<<<(NN * 64 + 255) / 256, 256, 0, stream>>>(adj, rowptr, h_bf, a_s, a_d, xp_bf);
    dim3 gf(MPAD / 128, 2);
    gemm_final<<<gf, 256, 0, stream>>>(xp_bf, W1t, b1, out);
}